// Round 1
// baseline (104.125 us; speedup 1.0000x reference)
//
#include <hip/hip_runtime.h>

#define NB 8
#define NP 16
#define NS 256
#define NN 4096
#define NT 4
#define CHUNK (256*NT)          // 1024 n per block
#define NCHUNK (NN/CHUNK)       // 4
#define NBLK (NB*NP*NCHUNK)     // 512
#define EPSV 1e-6f

__global__ void sqreg_init(unsigned int* __restrict__ minN, float* __restrict__ partials) {
    int i = blockIdx.x * 256 + threadIdx.x;
    if (i < NB*NP*NS) minN[i] = 0x7F800000u;  // +inf
    if (i < NBLK) partials[i] = 0.0f;
}

__global__ __launch_bounds__(256) void sqreg_main(
    const float* __restrict__ sp,     // (B,P,S,3)
    const float* __restrict__ pts,    // (B,N,3)
    const float* __restrict__ assign, // (B,N,P)
    unsigned int* __restrict__ minN,  // (B,P,S) as uint bits
    float* __restrict__ partials)     // NBLK
{
    __shared__ float4 lsp[NS];      // x,y,z,a2
    __shared__ float wmin[4][NS];   // per-wave min over its n-subset, per s
    __shared__ float psum[4];

    const int bid   = blockIdx.x;
    const int chunk = bid % NCHUNK;
    const int bp    = bid / NCHUNK;
    const int p     = bp % NP;
    const int b     = bp / NP;
    const int tid   = threadIdx.x;
    const int lane  = tid & 63;
    const int wave  = tid >> 6;

    // Stage surface points + |a|^2 in LDS
    {
        const float* s3 = sp + (size_t)((b*NP + p)*NS) * 3;
        float x = s3[tid*3+0], y = s3[tid*3+1], z = s3[tid*3+2];
        lsp[tid] = make_float4(x, y, z, x*x + y*y + z*z);
    }
    __syncthreads();

    // Per-thread n values (coalesced: n = base + tid + k*256)
    float px[NT], py[NT], pz[NT], pb2[NT], minS[NT];
    const int n0 = chunk*CHUNK + tid;
#pragma unroll
    for (int k = 0; k < NT; ++k) {
        int n = n0 + k*256;
        const float* q = pts + (size_t)(b*NN + n) * 3;
        px[k] = q[0]; py[k] = q[1]; pz[k] = q[2];
        pb2[k] = px[k]*px[k] + py[k]*py[k] + pz[k]*pz[k];
        minS[k] = INFINITY;
    }

#pragma unroll 4
    for (int s = 0; s < NS; ++s) {
        float4 v = lsp[s];              // broadcast read, conflict-free
        float tmin = INFINITY;
#pragma unroll
        for (int k = 0; k < NT; ++k) {
            float dot = v.x*px[k] + v.y*py[k] + v.z*pz[k];
            float d2  = fmaxf(v.w + pb2[k] - 2.0f*dot, 0.0f);
            minS[k] = fminf(minS[k], d2);
            tmin    = fminf(tmin, d2);
        }
        // wave-wide min over 64 lanes (covers this wave's 64*NT n values)
#pragma unroll
        for (int m = 32; m >= 1; m >>= 1)
            tmin = fminf(tmin, __shfl_xor(tmin, m, 64));
        if (lane == 0) wmin[wave][s] = tmin;   // per-wave slot: no race, no barrier
    }
    __syncthreads();

    // Combine 4 waves per s, push to global min (order-independent => deterministic)
    {
        float m = fminf(fminf(wmin[0][tid], wmin[1][tid]),
                        fminf(wmin[2][tid], wmin[3][tid]));
        atomicMin(&minN[(b*NP + p)*NS + tid], __float_as_uint(m));
    }

    // point_to_sq partial: sum_k minS[k] * assign[b, n_k, p]
    float acc = 0.0f;
#pragma unroll
    for (int k = 0; k < NT; ++k) {
        int n = n0 + k*256;
        acc += minS[k] * assign[(size_t)(b*NN + n)*NP + p];
    }
#pragma unroll
    for (int m = 32; m >= 1; m >>= 1)
        acc += __shfl_xor(acc, m, 64);
    if (lane == 0) psum[wave] = acc;
    __syncthreads();
    if (tid == 0) partials[bid] = psum[0] + psum[1] + psum[2] + psum[3];
}

__global__ __launch_bounds__(256) void sqreg_finalize(
    const unsigned int* __restrict__ minN,
    const float* __restrict__ partials,
    const float* __restrict__ exist,   // (B,P)
    float* __restrict__ out)
{
    __shared__ float s2p[NB*NP];
    __shared__ float wsum[4];
    const int tid = threadIdx.x;

    // Deterministic reduce of block partials
    float a = 0.0f;
    for (int i = tid; i < NBLK; i += 256) a += partials[i];
#pragma unroll
    for (int m = 32; m >= 1; m >>= 1)
        a += __shfl_xor(a, m, 64);
    if ((tid & 63) == 0) wsum[tid >> 6] = a;

    // s2p[b,p] = mean over s of min-over-n
    if (tid < NB*NP) {
        const unsigned int* base = minN + tid*NS;
        float ssum = 0.0f;
        for (int s = 0; s < NS; ++s) ssum += __uint_as_float(base[s]);
        s2p[tid] = ssum / (float)NS;
    }
    __syncthreads();

    if (tid == 0) {
        float total = wsum[0] + wsum[1] + wsum[2] + wsum[3];
        float point_to_sq = total / (float)(NB*NN);
        float sq = 0.0f;
        for (int b = 0; b < NB; ++b) {
            float den = 0.0f, num = 0.0f;
            for (int p = 0; p < NP; ++p) {
                float e = exist[b*NP + p];
                den += e;
                num += s2p[b*NP + p] * e;
            }
            sq += num / fmaxf(den, EPSV);
        }
        out[0] = point_to_sq + sq / (float)NB;
    }
}

extern "C" void kernel_launch(void* const* d_in, const int* in_sizes, int n_in,
                              void* d_out, int out_size, void* d_ws, size_t ws_size,
                              hipStream_t stream) {
    const float* sp     = (const float*)d_in[0];
    const float* pts    = (const float*)d_in[1];
    const float* assign = (const float*)d_in[2];
    const float* exist  = (const float*)d_in[3];
    float* out = (float*)d_out;

    unsigned int* minN = (unsigned int*)d_ws;
    float* partials    = (float*)d_ws + NB*NP*NS;

    sqreg_init<<<(NB*NP*NS + 255)/256, 256, 0, stream>>>(minN, partials);
    sqreg_main<<<NBLK, 256, 0, stream>>>(sp, pts, assign, minN, partials);
    sqreg_finalize<<<1, 256, 0, stream>>>(minN, partials, exist, out);
}

// Round 2
// 50.637 us; speedup vs baseline: 2.0563x; 2.0563x over previous
//
#include <hip/hip_runtime.h>

#define NB 8
#define NP 16
#define NS 256
#define NN 4096
#define NCHUNK 8
#define CHUNK (NN/NCHUNK)       // 512 n per block
#define NT (CHUNK/256)          // 2 n per thread (phase 1)
#define NBLK (NB*NP*NCHUNK)     // 1024
#define EPSV 1e-6f

__global__ void sqreg_init(unsigned int* __restrict__ minN, float* __restrict__ partials) {
    int i = blockIdx.x * 256 + threadIdx.x;
    if (i < NB*NP*NS) minN[i] = 0x7F800000u;  // +inf
    if (i < NBLK) partials[i] = 0.0f;
}

__global__ __launch_bounds__(256) void sqreg_main(
    const float* __restrict__ sp,     // (B,P,S,3)
    const float* __restrict__ pts,    // (B,N,3)
    const float* __restrict__ assign, // (B,N,P)
    unsigned int* __restrict__ minN,  // (B,P,S) as uint bits
    float* __restrict__ partials)     // NBLK
{
    __shared__ float4 lsp[NS];      // surface: x,y,z,|a|^2
    __shared__ float4 lpt[CHUNK];   // points:  x,y,z,|b|^2
    __shared__ float psum[4];

    const int bid   = blockIdx.x;
    const int chunk = bid % NCHUNK;
    const int bp    = bid / NCHUNK;
    const int p     = bp % NP;
    const int b     = bp / NP;
    const int tid   = threadIdx.x;
    const int lane  = tid & 63;
    const int wave  = tid >> 6;

    // Stage surface samples (s = tid) and this chunk's points in LDS
    {
        const float* s3 = sp + (size_t)(bp*NS) * 3;
        float x = s3[tid*3+0], y = s3[tid*3+1], z = s3[tid*3+2];
        lsp[tid] = make_float4(x, y, z, x*x + y*y + z*z);
        const float* q3 = pts + (size_t)(b*NN + chunk*CHUNK) * 3;
#pragma unroll
        for (int k = 0; k < NT; ++k) {
            int i = tid + k*256;
            float qx = q3[i*3+0], qy = q3[i*3+1], qz = q3[i*3+2];
            lpt[i] = make_float4(qx, qy, qz, qx*qx + qy*qy + qz*qz);
        }
    }
    __syncthreads();

    // ---- Phase 1: thread owns NT n's, min over all s in registers ----
    float px[NT], py[NT], pz[NT], pc[NT], mn[NT];
#pragma unroll
    for (int k = 0; k < NT; ++k) {
        float4 q = lpt[tid + k*256];
        px[k] = q.x; py[k] = q.y; pz[k] = q.z; pc[k] = q.w;
        mn[k] = INFINITY;
    }
#pragma unroll 4
    for (int s = 0; s < NS; ++s) {
        float4 v = lsp[s];          // uniform broadcast, conflict-free
#pragma unroll
        for (int k = 0; k < NT; ++k) {
            float dot = v.x*px[k];
            dot = fmaf(v.y, py[k], dot);
            dot = fmaf(v.z, pz[k], dot);
            float d2 = fmaf(-2.0f, dot, v.w + pc[k]);
            mn[k] = fminf(mn[k], d2);
        }
    }
    // weighted partial: clamp hoisted out of loop (max(0,min) == min(max(0,.)))
    float acc = 0.0f;
#pragma unroll
    for (int k = 0; k < NT; ++k) {
        int n = chunk*CHUNK + tid + k*256;
        acc += fmaxf(mn[k], 0.0f) * assign[(size_t)(b*NN + n)*NP + p];
    }

    // ---- Phase 2: thread owns s = tid, min over this chunk's n in registers ----
    float4 a = lsp[tid];
    float m0 = INFINITY, m1 = INFINITY, m2 = INFINITY, m3 = INFINITY;
#pragma unroll 2
    for (int n = 0; n < CHUNK; n += 4) {
        float4 q0 = lpt[n+0], q1 = lpt[n+1], q2 = lpt[n+2], q3 = lpt[n+3];
        float d;
        d = fmaf(-2.0f, fmaf(a.z,q0.z, fmaf(a.y,q0.y, a.x*q0.x)), a.w + q0.w); m0 = fminf(m0, d);
        d = fmaf(-2.0f, fmaf(a.z,q1.z, fmaf(a.y,q1.y, a.x*q1.x)), a.w + q1.w); m1 = fminf(m1, d);
        d = fmaf(-2.0f, fmaf(a.z,q2.z, fmaf(a.y,q2.y, a.x*q2.x)), a.w + q2.w); m2 = fminf(m2, d);
        d = fmaf(-2.0f, fmaf(a.z,q3.z, fmaf(a.y,q3.y, a.x*q3.x)), a.w + q3.w); m3 = fminf(m3, d);
    }
    float m = fmaxf(fminf(fminf(m0, m1), fminf(m2, m3)), 0.0f);
    atomicMin(&minN[bp*NS + tid], __float_as_uint(m));   // order-independent

    // ---- block reduction of phase-1 partial ----
#pragma unroll
    for (int msk = 32; msk >= 1; msk >>= 1)
        acc += __shfl_xor(acc, msk, 64);
    if (lane == 0) psum[wave] = acc;
    __syncthreads();
    if (tid == 0) partials[bid] = psum[0] + psum[1] + psum[2] + psum[3];
}

__global__ __launch_bounds__(256) void sqreg_finalize(
    const unsigned int* __restrict__ minN,
    const float* __restrict__ partials,
    const float* __restrict__ exist,   // (B,P)
    float* __restrict__ out)
{
    __shared__ float s2p[NB*NP];
    __shared__ float wsum[4];
    const int tid = threadIdx.x;

    float a = 0.0f;
    for (int i = tid; i < NBLK; i += 256) a += partials[i];
#pragma unroll
    for (int m = 32; m >= 1; m >>= 1)
        a += __shfl_xor(a, m, 64);
    if ((tid & 63) == 0) wsum[tid >> 6] = a;

    if (tid < NB*NP) {
        const unsigned int* base = minN + tid*NS;
        float ssum = 0.0f;
        for (int s = 0; s < NS; ++s) ssum += __uint_as_float(base[s]);
        s2p[tid] = ssum / (float)NS;
    }
    __syncthreads();

    if (tid == 0) {
        float total = wsum[0] + wsum[1] + wsum[2] + wsum[3];
        float point_to_sq = total / (float)(NB*NN);
        float sq = 0.0f;
        for (int b = 0; b < NB; ++b) {
            float den = 0.0f, num = 0.0f;
            for (int p = 0; p < NP; ++p) {
                float e = exist[b*NP + p];
                den += e;
                num += s2p[b*NP + p] * e;
            }
            sq += num / fmaxf(den, EPSV);
        }
        out[0] = point_to_sq + sq / (float)NB;
    }
}

extern "C" void kernel_launch(void* const* d_in, const int* in_sizes, int n_in,
                              void* d_out, int out_size, void* d_ws, size_t ws_size,
                              hipStream_t stream) {
    const float* sp     = (const float*)d_in[0];
    const float* pts    = (const float*)d_in[1];
    const float* assign = (const float*)d_in[2];
    const float* exist  = (const float*)d_in[3];
    float* out = (float*)d_out;

    unsigned int* minN = (unsigned int*)d_ws;
    float* partials    = (float*)d_ws + NB*NP*NS;

    sqreg_init<<<(NB*NP*NS + 255)/256, 256, 0, stream>>>(minN, partials);
    sqreg_main<<<NBLK, 256, 0, stream>>>(sp, pts, assign, minN, partials);
    sqreg_finalize<<<1, 256, 0, stream>>>(minN, partials, exist, out);
}

// Round 3
// 49.940 us; speedup vs baseline: 2.0850x; 1.0140x over previous
//
#include <hip/hip_runtime.h>

#define NB 8
#define NP 16
#define NS 256
#define NN 4096
#define NBP (NB*NP)             // 128
#define NCHUNK 4
#define CHUNK (NN/NCHUNK)       // 1024 n per block
#define NT (CHUNK/256)          // 4 n per thread (phase 1)
#define NBLK (NBP*NCHUNK)       // 512
#define EPSV 1e-6f

// ---------------- workspace layout (bytes) ----------------
// spt4  : float4[NBP*NS]        @ 0          (512 KB)  (x,y,z,|a|^2)
// pts4  : float4[NB*NN]         @ 0x80000    (512 KB)  (-2x,-2y,-2z,|b|^2)
// minw  : float [NBLK*NS]       @ 0x100000   (512 KB)
// part  : float [NBLK]          @ 0x180000
// s2p   : float [NBP]           @ 0x180000 + 4*NBLK
// pp    : float [NBP]           @ ... + 4*NBP

__global__ __launch_bounds__(256) void sqreg_prep(
    const float* __restrict__ sp, const float* __restrict__ pts,
    float4* __restrict__ spt4, float4* __restrict__ pts4)
{
    int i = blockIdx.x * 256 + threadIdx.x;
    if (i < NBP*NS) {
        float x = sp[i*3+0], y = sp[i*3+1], z = sp[i*3+2];
        spt4[i] = make_float4(x, y, z, x*x + y*y + z*z);
    } else {
        int j = i - NBP*NS;   // < NB*NN
        float x = pts[j*3+0], y = pts[j*3+1], z = pts[j*3+2];
        pts4[j] = make_float4(-2.0f*x, -2.0f*y, -2.0f*z, x*x + y*y + z*z);
    }
}

__global__ __launch_bounds__(256) void sqreg_main(
    const float4* __restrict__ spt4,  // (BP, S)
    const float4* __restrict__ pts4,  // (B, N)
    const float* __restrict__ assign, // (B, N, P)
    float* __restrict__ minw,         // (NBLK, S)
    float* __restrict__ partials)     // NBLK
{
    __shared__ float4 lsp[NS];      // surface: x,y,z,|a|^2
    __shared__ float4 lpt[CHUNK];   // points:  -2x,-2y,-2z,|b|^2
    __shared__ float psum[4];

    const int bid   = blockIdx.x;
    const int chunk = bid % NCHUNK;
    const int bp    = bid / NCHUNK;
    const int p     = bp % NP;
    const int b     = bp / NP;
    const int tid   = threadIdx.x;
    const int lane  = tid & 63;
    const int wave  = tid >> 6;

    lsp[tid] = spt4[bp*NS + tid];
#pragma unroll
    for (int k = 0; k < NT; ++k) {
        int i = tid + k*256;
        lpt[i] = pts4[b*NN + chunk*CHUNK + i];
    }
    __syncthreads();

    // ---- Phase 1: thread owns NT n's; min over s of (|a|^2 - 2 a.b) ----
    float qx[NT], qy[NT], qz[NT], qw[NT], mn[NT];
#pragma unroll
    for (int k = 0; k < NT; ++k) {
        float4 q = lpt[tid + k*256];
        qx[k] = q.x; qy[k] = q.y; qz[k] = q.z; qw[k] = q.w;
        mn[k] = INFINITY;
    }
#pragma unroll 2
    for (int s = 0; s < NS; s += 2) {
        float4 v0 = lsp[s], v1 = lsp[s+1];
#pragma unroll
        for (int k = 0; k < NT; ++k) {
            float g0 = fmaf(qx[k], v0.x, fmaf(qy[k], v0.y, fmaf(qz[k], v0.z, v0.w)));
            float g1 = fmaf(qx[k], v1.x, fmaf(qy[k], v1.y, fmaf(qz[k], v1.z, v1.w)));
            mn[k] = fminf(fminf(g0, g1), mn[k]);   // -> v_min3_f32
        }
    }
    float acc = 0.0f;
#pragma unroll
    for (int k = 0; k < NT; ++k) {
        int n = chunk*CHUNK + tid + k*256;
        acc += fmaxf(mn[k] + qw[k], 0.0f) * assign[(size_t)(b*NN + n)*NP + p];
    }

    // ---- Phase 2: threads 0..127 own s=tid and s=tid+128; min over chunk n ----
    if (tid < 128) {
        float4 a0 = lsp[tid], a1 = lsp[tid + 128];
        float m0 = INFINITY, m1 = INFINITY;
#pragma unroll 4
        for (int n = 0; n < CHUNK; n += 2) {
            float4 u0 = lpt[n], u1 = lpt[n+1];
            float h00 = fmaf(u0.x, a0.x, fmaf(u0.y, a0.y, fmaf(u0.z, a0.z, u0.w)));
            float h01 = fmaf(u1.x, a0.x, fmaf(u1.y, a0.y, fmaf(u1.z, a0.z, u1.w)));
            m0 = fminf(fminf(h00, h01), m0);
            float h10 = fmaf(u0.x, a1.x, fmaf(u0.y, a1.y, fmaf(u0.z, a1.z, u0.w)));
            float h11 = fmaf(u1.x, a1.x, fmaf(u1.y, a1.y, fmaf(u1.z, a1.z, u1.w)));
            m1 = fminf(fminf(h10, h11), m1);
        }
        minw[bid*NS + tid]       = fmaxf(m0 + a0.w, 0.0f);
        minw[bid*NS + tid + 128] = fmaxf(m1 + a1.w, 0.0f);
    }

    // ---- block reduction of phase-1 partial ----
#pragma unroll
    for (int msk = 32; msk >= 1; msk >>= 1)
        acc += __shfl_xor(acc, msk, 64);
    if (lane == 0) psum[wave] = acc;
    __syncthreads();
    if (tid == 0) partials[bid] = psum[0] + psum[1] + psum[2] + psum[3];
}

__global__ __launch_bounds__(256) void sqreg_reduce(
    const float* __restrict__ minw,     // (NBLK, S)
    const float* __restrict__ partials, // NBLK
    float* __restrict__ s2p,            // NBP
    float* __restrict__ pp)             // NBP
{
    __shared__ float wsum[4];
    const int bp  = blockIdx.x;
    const int tid = threadIdx.x;

    const float* base = minw + (size_t)(bp*NCHUNK)*NS + tid;
    float m = base[0];
#pragma unroll
    for (int c = 1; c < NCHUNK; ++c) m = fminf(m, base[c*NS]);

#pragma unroll
    for (int msk = 32; msk >= 1; msk >>= 1)
        m += __shfl_xor(m, msk, 64);
    if ((tid & 63) == 0) wsum[tid >> 6] = m;
    __syncthreads();
    if (tid == 0) {
        s2p[bp] = (wsum[0] + wsum[1] + wsum[2] + wsum[3]) / (float)NS;
        float a = 0.0f;
#pragma unroll
        for (int c = 0; c < NCHUNK; ++c) a += partials[bp*NCHUNK + c];
        pp[bp] = a;
    }
}

__global__ __launch_bounds__(256) void sqreg_final(
    const float* __restrict__ s2p,
    const float* __restrict__ pp,
    const float* __restrict__ exist,   // (B,P)
    float* __restrict__ out)
{
    __shared__ float wsum[2];
    const int tid = threadIdx.x;

    float a = (tid < NBP) ? pp[tid] : 0.0f;
#pragma unroll
    for (int msk = 32; msk >= 1; msk >>= 1)
        a += __shfl_xor(a, msk, 64);
    if (tid == 0)  wsum[0] = a;
    if (tid == 64) wsum[1] = a;
    __syncthreads();

    if (tid == 0) {
        float point_to_sq = (wsum[0] + wsum[1]) / (float)(NB*NN);
        float sq = 0.0f;
        for (int b = 0; b < NB; ++b) {
            float den = 0.0f, num = 0.0f;
            for (int q = 0; q < NP; ++q) {
                float e = exist[b*NP + q];
                den += e;
                num += s2p[b*NP + q] * e;
            }
            sq += num / fmaxf(den, EPSV);
        }
        out[0] = point_to_sq + sq / (float)NB;
    }
}

extern "C" void kernel_launch(void* const* d_in, const int* in_sizes, int n_in,
                              void* d_out, int out_size, void* d_ws, size_t ws_size,
                              hipStream_t stream) {
    const float* sp     = (const float*)d_in[0];
    const float* pts    = (const float*)d_in[1];
    const float* assign = (const float*)d_in[2];
    const float* exist  = (const float*)d_in[3];
    float* out = (float*)d_out;

    char* ws = (char*)d_ws;
    float4* spt4    = (float4*)(ws);
    float4* pts4    = (float4*)(ws + 0x80000);
    float*  minw    = (float* )(ws + 0x100000);
    float*  part    = (float* )(ws + 0x180000);
    float*  s2p     = (float* )(ws + 0x180000 + 4*NBLK);
    float*  pp      = (float* )(ws + 0x180000 + 4*NBLK + 4*NBP);

    sqreg_prep  <<<(NBP*NS + NB*NN)/256, 256, 0, stream>>>(sp, pts, spt4, pts4);
    sqreg_main  <<<NBLK, 256, 0, stream>>>(spt4, pts4, assign, minw, part);
    sqreg_reduce<<<NBP, 256, 0, stream>>>(minw, part, s2p, pp);
    sqreg_final <<<1, 256, 0, stream>>>(s2p, pp, exist, out);
}

// Round 4
// 40.428 us; speedup vs baseline: 2.5755x; 1.2353x over previous
//
#include <hip/hip_runtime.h>

#define NB 8
#define NP 16
#define NS 256
#define NN 4096
#define NBP (NB*NP)             // 128
#define NCHUNK 8
#define CHUNK (NN/NCHUNK)       // 512 n per block
#define NT (CHUNK/256)          // 2 n per thread (phase 1)
#define NBLK (NBP*NCHUNK)       // 1024
#define EPSV 1e-6f

// ---------------- workspace layout (bytes) ----------------
// minw : float[NBLK*NS]  @ 0          (1 MB)
// part : float[NBLK]     @ 0x100000   (4 KB)
// s2p  : float[NBP]      @ 0x101000
// pp   : float[NBP]      @ 0x101400
// cnt  : uint            @ 0x101800

__global__ __launch_bounds__(256) void sqreg_main(
    const float* __restrict__ sp,     // (B,P,S,3)
    const float* __restrict__ pts,    // (B,N,3)
    const float* __restrict__ assign, // (B,N,P)
    float* __restrict__ minw,         // (NBLK, S)
    float* __restrict__ partials,     // NBLK
    unsigned int* __restrict__ cnt)
{
    __shared__ float4 lsp[NS];      // surface: x,y,z,|a|^2
    __shared__ float4 lpt[CHUNK];   // points:  -2x,-2y,-2z,|b|^2
    __shared__ float psum[4];

    const int bid   = blockIdx.x;
    const int chunk = bid % NCHUNK;
    const int bp    = bid / NCHUNK;
    const int p     = bp % NP;
    const int b     = bp / NP;
    const int tid   = threadIdx.x;
    const int lane  = tid & 63;
    const int wave  = tid >> 6;

    if (bid == 0 && tid == 0) *cnt = 0u;   // reset tail counter (stream-ordered before tail)

    // Stage + prescale directly from inputs (prep kernel folded in)
    {
        const float* s3 = sp + (size_t)(bp*NS)*3;
        float x = s3[tid*3+0], y = s3[tid*3+1], z = s3[tid*3+2];
        lsp[tid] = make_float4(x, y, z, x*x + y*y + z*z);
        const float* q3 = pts + (size_t)(b*NN + chunk*CHUNK)*3;
#pragma unroll
        for (int k = 0; k < NT; ++k) {
            int i = tid + k*256;
            float qx = q3[i*3+0], qy = q3[i*3+1], qz = q3[i*3+2];
            lpt[i] = make_float4(-2.0f*qx, -2.0f*qy, -2.0f*qz, qx*qx + qy*qy + qz*qz);
        }
    }
    __syncthreads();

    // ---- Phase 1: thread owns NT n's; min over s of (|a|^2 - 2 a.b) ----
    float qx[NT], qy[NT], qz[NT], qw[NT], mn[NT];
#pragma unroll
    for (int k = 0; k < NT; ++k) {
        float4 q = lpt[tid + k*256];
        qx[k] = q.x; qy[k] = q.y; qz[k] = q.z; qw[k] = q.w;
        mn[k] = INFINITY;
    }
#pragma unroll 2
    for (int s = 0; s < NS; s += 2) {
        float4 v0 = lsp[s], v1 = lsp[s+1];
#pragma unroll
        for (int k = 0; k < NT; ++k) {
            float g0 = fmaf(qx[k], v0.x, fmaf(qy[k], v0.y, fmaf(qz[k], v0.z, v0.w)));
            float g1 = fmaf(qx[k], v1.x, fmaf(qy[k], v1.y, fmaf(qz[k], v1.z, v1.w)));
            mn[k] = fminf(fminf(g0, g1), mn[k]);   // v_min3_f32
        }
    }
    float acc = 0.0f;
#pragma unroll
    for (int k = 0; k < NT; ++k) {
        int n = chunk*CHUNK + tid + k*256;
        acc += fmaxf(mn[k] + qw[k], 0.0f) * assign[(size_t)(b*NN + n)*NP + p];
    }

    // ---- Phase 2: ALL threads; thread owns s = tid; min over chunk n ----
    {
        float4 a = lsp[tid];
        float m0 = INFINITY, m1 = INFINITY;
#pragma unroll 4
        for (int n = 0; n < CHUNK; n += 4) {
            float4 u0 = lpt[n+0], u1 = lpt[n+1], u2 = lpt[n+2], u3 = lpt[n+3];
            float h0 = fmaf(u0.x, a.x, fmaf(u0.y, a.y, fmaf(u0.z, a.z, u0.w)));
            float h1 = fmaf(u1.x, a.x, fmaf(u1.y, a.y, fmaf(u1.z, a.z, u1.w)));
            m0 = fminf(fminf(h0, h1), m0);
            float h2 = fmaf(u2.x, a.x, fmaf(u2.y, a.y, fmaf(u2.z, a.z, u2.w)));
            float h3 = fmaf(u3.x, a.x, fmaf(u3.y, a.y, fmaf(u3.z, a.z, u3.w)));
            m1 = fminf(fminf(h2, h3), m1);
        }
        minw[(size_t)bid*NS + tid] = fmaxf(fminf(m0, m1) + a.w, 0.0f);
    }

    // ---- block reduction of phase-1 partial ----
#pragma unroll
    for (int msk = 32; msk >= 1; msk >>= 1)
        acc += __shfl_xor(acc, msk, 64);
    if (lane == 0) psum[wave] = acc;
    __syncthreads();
    if (tid == 0) partials[bid] = psum[0] + psum[1] + psum[2] + psum[3];
}

__global__ __launch_bounds__(256) void sqreg_tail(
    const float* __restrict__ minw,     // (NBLK, S)
    const float* __restrict__ partials, // NBLK
    const float* __restrict__ exist,    // (B,P)
    float* __restrict__ s2p,            // NBP
    float* __restrict__ pp,             // NBP
    unsigned int* __restrict__ cnt,
    float* __restrict__ out)
{
    __shared__ float wsum[4];
    const int bp   = blockIdx.x;
    const int tid  = threadIdx.x;
    const int lane = tid & 63;
    const int wave = tid >> 6;

    // min over this bp's chunks for s = tid, then sum over s
    const float* base = minw + (size_t)(bp*NCHUNK)*NS + tid;
    float m = base[0];
#pragma unroll
    for (int c = 1; c < NCHUNK; ++c) m = fminf(m, base[(size_t)c*NS]);
#pragma unroll
    for (int msk = 32; msk >= 1; msk >>= 1)
        m += __shfl_xor(m, msk, 64);
    if (lane == 0) wsum[wave] = m;
    __syncthreads();

    if (tid == 0) {
        s2p[bp] = (wsum[0] + wsum[1] + wsum[2] + wsum[3]) * (1.0f/(float)NS);
        float a = 0.0f;
#pragma unroll
        for (int c = 0; c < NCHUNK; ++c) a += partials[bp*NCHUNK + c];
        pp[bp] = a;
        __threadfence();                       // release s2p/pp
        if (atomicAdd(cnt, 1u) == NBP - 1) {   // last block finishes the scalar tail
            __threadfence();                   // acquire other blocks' s2p/pp
            float total = 0.0f;
#pragma unroll
            for (int i = 0; i < NBP; ++i) total += pp[i];
            float point_to_sq = total / (float)((size_t)NB*NN);
            float sq = 0.0f;
            for (int bb = 0; bb < NB; ++bb) {
                float den = 0.0f, num = 0.0f;
#pragma unroll
                for (int q = 0; q < NP; ++q) {
                    float e = exist[bb*NP + q];
                    den += e;
                    num += s2p[bb*NP + q] * e;
                }
                sq += num / fmaxf(den, EPSV);
            }
            out[0] = point_to_sq + sq * (1.0f/(float)NB);
        }
    }
}

extern "C" void kernel_launch(void* const* d_in, const int* in_sizes, int n_in,
                              void* d_out, int out_size, void* d_ws, size_t ws_size,
                              hipStream_t stream) {
    const float* sp     = (const float*)d_in[0];
    const float* pts    = (const float*)d_in[1];
    const float* assign = (const float*)d_in[2];
    const float* exist  = (const float*)d_in[3];
    float* out = (float*)d_out;

    char* ws = (char*)d_ws;
    float*        minw = (float*)(ws);
    float*        part = (float*)(ws + 0x100000);
    float*        s2p  = (float*)(ws + 0x101000);
    float*        pp   = (float*)(ws + 0x101400);
    unsigned int* cnt  = (unsigned int*)(ws + 0x101800);

    sqreg_main<<<NBLK, 256, 0, stream>>>(sp, pts, assign, minw, part, cnt);
    sqreg_tail<<<NBP, 256, 0, stream>>>(minw, part, exist, s2p, pp, cnt, out);
}